// Round 3
// baseline (356.468 us; speedup 1.0000x reference)
//
#include <hip/hip_runtime.h>
#include <stdint.h>
#include <stddef.h>

#define TEMP      0.05f
#define INV_TEMP  20.0f     // 1/TEMP
#define MOMENTUM  0.2f
#define SMOOTH    0.1f
#define TAU_W     0.09f
#define NSAMP     100000
#define NFEAT     256
#define BATCH     256
#define SHIFT     20.0f     // fixed logit shift: |dot/TEMP| <= ~20.2, so exp(l-20) never overflows
#define MT        64        // feature rows per block in k_main

typedef float  f32x4  __attribute__((ext_vector_type(4)));
typedef float  f32x2  __attribute__((ext_vector_type(2)));
typedef short  short8 __attribute__((ext_vector_type(8)));
typedef unsigned int u32x2 __attribute__((ext_vector_type(2)));

// fp32 -> bf16 round-to-nearest-even
__device__ __forceinline__ short f2bf(float f) {
    uint32_t u = __builtin_bit_cast(uint32_t, f);
    u = (u + 0x7fffu + ((u >> 16) & 1u)) >> 16;
    return (short)u;
}

// D = A*B + D, 16x16x32 bf16 (known-good from round 2)
__device__ __forceinline__ void mfma_bf16(f32x4& c, short8 a, short8 b) {
    asm("v_mfma_f32_16x16x32_bf16 %0, %1, %2, %0" : "+v"(c) : "v"(a), "v"(b));
}

// 256-thread (4-wave) block sum reduction; scratch needs >= 5 floats
__device__ __forceinline__ float block_reduce_sum256(float v, float* scratch) {
    for (int o = 32; o > 0; o >>= 1) v += __shfl_down(v, o, 64);
    int lane = threadIdx.x & 63, wid = threadIdx.x >> 6;
    if (lane == 0) scratch[wid] = v;
    __syncthreads();
    if (threadIdx.x == 0)
        scratch[4] = scratch[0] + scratch[1] + scratch[2] + scratch[3];
    __syncthreads();
    return scratch[4];
}

// ---------------------------------------------------------------------------
// K0: pure streaming copy F -> out+2 (fp32). NT stores keep L2 clean; normal
// loads pull F into L3 so k_main's staging reads are L3-hot.
// ---------------------------------------------------------------------------
__global__ void __launch_bounds__(256)
k_copy(const float* __restrict__ F, float* __restrict__ out) {
    const size_t total = (size_t)NSAMP * NFEAT / 4;   // 6.4M f32x4 chunks
    size_t stride = (size_t)gridDim.x * 256;
    for (size_t i = (size_t)blockIdx.x * 256 + threadIdx.x; i < total; i += stride) {
        f32x4 v = *(const f32x4*)(F + i * 4);
        float* op = out + 2 + i * 4;              // +2 -> only 8B aligned
        __builtin_nontemporal_store(f32x2{v[0], v[1]}, (f32x2*)op);
        __builtin_nontemporal_store(f32x2{v[2], v[3]}, (f32x2*)(op + 2));
    }
}

// ---------------------------------------------------------------------------
// K1: normalize x1/x2, emit bf16 X (pair-interleaved layout), exact d[b], zero accums.
// X layout: group g = b/32 owns rows [g*64, g*64+64): rows g*64 + (b%32)      = x1n[b]
//                                                     rows g*64 + 32 + (b%32) = x2n[b]
// ---------------------------------------------------------------------------
__global__ void k_prep(const float* __restrict__ in1, const float* __restrict__ in2,
                       const float* __restrict__ F, const int* __restrict__ tgt,
                       float* __restrict__ x1n, short* __restrict__ Xb,
                       float* __restrict__ dvec,
                       float* __restrict__ Z1, float* __restrict__ Z2, float* __restrict__ S12) {
    __shared__ float scratch[8];
    int b = blockIdx.x;
    int k = threadIdx.x;
    float v1 = in1[b * NFEAT + k];
    float v2 = in2[b * NFEAT + k];
    float n1 = block_reduce_sum256(v1 * v1, scratch);
    float n2 = block_reduce_sum256(v2 * v2, scratch);
    float x1 = v1 / fmaxf(sqrtf(n1), 1e-12f);
    float x2 = v2 / fmaxf(sqrtf(n2), 1e-12f);
    x1n[b * NFEAT + k] = x1;
    int g = b >> 5, r = b & 31;
    Xb[(g * 64 + r) * NFEAT + k]      = f2bf(x1);
    Xb[(g * 64 + 32 + r) * NFEAT + k] = f2bf(x2);
    int t = tgt[b];
    float dv = block_reduce_sum256(x1 * F[(size_t)t * NFEAT + k], scratch);
    if (k == 0) {
        dvec[b] = dv;
        Z1[b] = 0.f; Z2[b] = 0.f; S12[b] = 0.f;
    }
}

// ---------------------------------------------------------------------------
// K2: bf16 MFMA logits + shifted-exp reductions (copy removed -> pure compute).
// Staging is two-phase: issue ALL 8 f32x4 loads, then convert+LDS-write, so the
// 8 loads stay in flight together (no store-drain in the dependency chain).
// ---------------------------------------------------------------------------
__global__ void __launch_bounds__(512)
k_main(const float* __restrict__ F, const short* __restrict__ Xb,
       float* __restrict__ Z1, float* __restrict__ Z2, float* __restrict__ S12) {
    __shared__ short lfs[MT * NFEAT];  // 32 KB, row stride 512 B, byte-XOR swizzle ((row&7)<<4)
    int tid = threadIdx.x;
    int m0 = blockIdx.x * MT;

    // phase 1: issue all loads
    f32x4 v[8];
    #pragma unroll
    for (int rr = 0; rr < 8; ++rr) {
        int c   = rr * 512 + tid;
        int row = c >> 6, cc = c & 63;
        int grow = m0 + row;
        v[rr] = f32x4{0.f, 0.f, 0.f, 0.f};
        if (grow < NSAMP)
            v[rr] = *(const f32x4*)(F + (size_t)grow * NFEAT + cc * 4);
    }
    // phase 2: convert + LDS write
    #pragma unroll
    for (int rr = 0; rr < 8; ++rr) {
        int c   = rr * 512 + tid;
        int row = c >> 6, cc = c & 63;
        uint32_t p0 = (uint32_t)(uint16_t)f2bf(v[rr][0]) | ((uint32_t)(uint16_t)f2bf(v[rr][1]) << 16);
        uint32_t p1 = (uint32_t)(uint16_t)f2bf(v[rr][2]) | ((uint32_t)(uint16_t)f2bf(v[rr][3]) << 16);
        int off = row * 512 + ((cc * 8) ^ ((row & 7) << 4));
        *(u32x2*)((char*)lfs + off) = (u32x2){p0, p1};
    }
    __syncthreads();

    int w = tid >> 6, lane = tid & 63;
    int l15 = lane & 15, lg = lane >> 4;

    f32x4 acc[4][4] = {};  // [m-frag][col-frag]
    const short* xbase = Xb + (size_t)(w * 64) * NFEAT;

    #pragma unroll
    for (int kk = 0; kk < 8; ++kk) {       // K = 256 in steps of 32
        int kb = kk * 64 + lg * 16;        // byte offset of this lane-group's 8 bf16 k-elems
        short8 a[4], bf[4];
        #pragma unroll
        for (int cf = 0; cf < 4; ++cf)
            bf[cf] = *(const short8*)(xbase + (cf * 16 + l15) * NFEAT + kk * 32 + lg * 8);
        #pragma unroll
        for (int mf = 0; mf < 4; ++mf) {
            int row = mf * 16 + l15;
            a[mf] = *(const short8*)((const char*)lfs + row * 512 + (kb ^ ((row & 7) << 4)));
        }
        #pragma unroll
        for (int mf = 0; mf < 4; ++mf)
            #pragma unroll
            for (int cf = 0; cf < 4; ++cf)
                mfma_bf16(acc[mf][cf], a[mf], bf[cf]);
    }

    // epilogue: fixed-shift exp + per-b reduction + atomics
    // C/D layout: col = lane&15, row = (lane>>4)*4 + q
    #pragma unroll
    for (int cf = 0; cf < 2; ++cf) {
        float z1 = 0.f, z2 = 0.f, s12 = 0.f;
        #pragma unroll
        for (int mf = 0; mf < 4; ++mf) {
            #pragma unroll
            for (int q = 0; q < 4; ++q) {
                int grow = m0 + mf * 16 + lg * 4 + q;
                if (grow < NSAMP) {
                    float l1 = acc[mf][cf][q] * INV_TEMP;
                    float e1 = __expf(l1 - SHIFT);
                    float e2 = __expf(acc[mf][cf + 2][q] * INV_TEMP - SHIFT);
                    z1 += e1; z2 += e2; s12 += e2 * l1;
                }
            }
        }
        z1  += __shfl_xor(z1, 16);  z1  += __shfl_xor(z1, 32);
        z2  += __shfl_xor(z2, 16);  z2  += __shfl_xor(z2, 32);
        s12 += __shfl_xor(s12, 16); s12 += __shfl_xor(s12, 32);
        if (lane < 16) {
            int b = w * 32 + cf * 16 + lane;
            atomicAdd(&Z1[b], z1);
            atomicAdd(&Z2[b], z2);
            atomicAdd(&S12[b], s12);
        }
    }
}

// ---------------------------------------------------------------------------
// K3: per-target-cluster weighted-mean update. tgt/dvec staged in LDS so the
// O(B) scans have no global-memory latency in the loop.
// ---------------------------------------------------------------------------
__global__ void k_update(const float* __restrict__ F, const int* __restrict__ tgt,
                         const float* __restrict__ dvec, const float* __restrict__ x1n,
                         float* __restrict__ out) {
    __shared__ int   stgt[BATCH];
    __shared__ float slog[BATCH];
    __shared__ float scratch[8];
    int b = blockIdx.x, k = threadIdx.x;
    stgt[k] = tgt[k];
    slog[k] = -dvec[k] * (1.0f / TAU_W);
    __syncthreads();
    int t = stgt[b];
    for (int bp = 0; bp < b; ++bp)
        if (stgt[bp] == t) return;   // uniform: only first occurrence owns cluster t
    float m = -1e30f;
    for (int bp = 0; bp < BATCH; ++bp)
        if (stgt[bp] == t) m = fmaxf(m, slog[bp]);
    float denom = 0.f;
    for (int bp = 0; bp < BATCH; ++bp)
        if (stgt[bp] == t) denom += expf(slog[bp] - m);
    float wmean = 0.f;
    for (int bp = 0; bp < BATCH; ++bp)
        if (stgt[bp] == t)
            wmean += expf(slog[bp] - m) * x1n[bp * NFEAT + k];
    wmean /= denom;
    float upd = MOMENTUM * F[(size_t)t * NFEAT + k] + (1.f - MOMENTUM) * wmean;
    float nrm = block_reduce_sum256(upd * upd, scratch);
    out[2 + (size_t)t * NFEAT + k] = upd / fmaxf(sqrtf(nrm), 1e-12f);
}

// ---------------------------------------------------------------------------
// K4: closed-form losses from the per-b statistics.
// ---------------------------------------------------------------------------
__global__ void k_loss(const float* __restrict__ dvec, const float* __restrict__ Z1,
                       const float* __restrict__ Z2, const float* __restrict__ S12,
                       float* __restrict__ out) {
    __shared__ float scratch[8];
    int b = threadIdx.x;
    float L1   = SHIFT + logf(Z1[b]);           // logsumexp of logits1 row b
    float lpt  = dvec[b] * INV_TEMP - L1;       // logp at target
    float ce12 = S12[b] / Z2[b];                // sum_n softmax(l2) * l1
    float lc = -lpt;
    float ls = (1.f - SMOOTH) * (L1 - ce12) + SMOOTH * (-lpt);
    float sc = block_reduce_sum256(lc, scratch);
    float ss = block_reduce_sum256(ls, scratch);
    if (b == 0) {
        out[0] = sc / (float)BATCH;
        out[1] = ss / (float)BATCH;
    }
}

extern "C" void kernel_launch(void* const* d_in, const int* in_sizes, int n_in,
                              void* d_out, int out_size, void* d_ws, size_t ws_size,
                              hipStream_t stream) {
    const float* in1 = (const float*)d_in[0];
    const float* in2 = (const float*)d_in[1];
    const float* F   = (const float*)d_in[2];
    const int*   tgt = (const int*)d_in[3];
    float* out = (float*)d_out;

    char* ws = (char*)d_ws;
    float* x1n = (float*)ws;                   // 256*256*4   = 262144 B
    short* Xb  = (short*)(ws + 262144);        // 512*256*2   = 262144 B
    float* dv  = (float*)(ws + 524288);        // 1 KB
    float* Z1  = (float*)(ws + 525312);        // 1 KB
    float* Z2  = (float*)(ws + 526336);        // 1 KB
    float* S12 = (float*)(ws + 527360);        // 1 KB

    hipLaunchKernelGGL(k_copy, dim3(2048), dim3(256), 0, stream, F, out);
    hipLaunchKernelGGL(k_prep, dim3(BATCH), dim3(256), 0, stream,
                       in1, in2, F, tgt, x1n, Xb, dv, Z1, Z2, S12);
    hipLaunchKernelGGL(k_main, dim3((NSAMP + MT - 1) / MT), dim3(512), 0, stream,
                       F, Xb, Z1, Z2, S12);
    hipLaunchKernelGGL(k_update, dim3(BATCH), dim3(256), 0, stream,
                       F, tgt, dv, x1n, out);
    hipLaunchKernelGGL(k_loss, dim3(1), dim3(256), 0, stream,
                       dv, Z1, Z2, S12, out);
}

// Round 4
// 345.516 us; speedup vs baseline: 1.0317x; 1.0317x over previous
//
#include <hip/hip_runtime.h>
#include <stdint.h>
#include <stddef.h>

#define TEMP      0.05f
#define INV_TEMP  20.0f     // 1/TEMP
#define MOMENTUM  0.2f
#define SMOOTH    0.1f
#define TAU_W     0.09f
#define NSAMP     100000
#define NFEAT     256
#define BATCH     256
#define SHIFT     20.0f     // fixed logit shift: |dot/TEMP| <= ~20.2
#define MT        64        // feature rows per block in k_main
#define NSHADOW   16        // de-contended atomic shadow copies

typedef float  f32x4  __attribute__((ext_vector_type(4)));
typedef float  f32x2  __attribute__((ext_vector_type(2)));
typedef short  short8 __attribute__((ext_vector_type(8)));
typedef unsigned int u32x2 __attribute__((ext_vector_type(2)));

// fp32 -> bf16 round-to-nearest-even
__device__ __forceinline__ short f2bf(float f) {
    uint32_t u = __builtin_bit_cast(uint32_t, f);
    u = (u + 0x7fffu + ((u >> 16) & 1u)) >> 16;
    return (short)u;
}

__device__ __forceinline__ void mfma_bf16(f32x4& c, short8 a, short8 b) {
    asm("v_mfma_f32_16x16x32_bf16 %0, %1, %2, %0" : "+v"(c) : "v"(a), "v"(b));
}

// 256-thread (4-wave) block sum reduction; scratch needs >= 5 floats
__device__ __forceinline__ float block_reduce_sum256(float v, float* scratch) {
    for (int o = 32; o > 0; o >>= 1) v += __shfl_down(v, o, 64);
    int lane = threadIdx.x & 63, wid = threadIdx.x >> 6;
    if (lane == 0) scratch[wid] = v;
    __syncthreads();
    if (threadIdx.x == 0)
        scratch[4] = scratch[0] + scratch[1] + scratch[2] + scratch[3];
    __syncthreads();
    return scratch[4];
}

// ---------------------------------------------------------------------------
// K0: streaming copy F -> out+2 (fp32). NT stores; loads warm L3 for k_main.
// ---------------------------------------------------------------------------
__global__ void __launch_bounds__(256)
k_copy(const float* __restrict__ F, float* __restrict__ out) {
    const size_t total = (size_t)NSAMP * NFEAT / 4;
    size_t stride = (size_t)gridDim.x * 256;
    for (size_t i = (size_t)blockIdx.x * 256 + threadIdx.x; i < total; i += stride) {
        f32x4 v = *(const f32x4*)(F + i * 4);
        float* op = out + 2 + i * 4;              // +2 -> only 8B aligned
        __builtin_nontemporal_store(f32x2{v[0], v[1]}, (f32x2*)op);
        __builtin_nontemporal_store(f32x2{v[2], v[3]}, (f32x2*)(op + 2));
    }
}

// ---------------------------------------------------------------------------
// K1: normalize x1/x2, emit bf16 X (pair-interleaved), exact d[b], zero shadows.
// Zs layout: [0,4096) Z1 shadows (16x256), [4096,8192) Z2, [8192,12288) S12.
// ---------------------------------------------------------------------------
__global__ void k_prep(const float* __restrict__ in1, const float* __restrict__ in2,
                       const float* __restrict__ F, const int* __restrict__ tgt,
                       float* __restrict__ x1n, short* __restrict__ Xb,
                       float* __restrict__ dvec, float* __restrict__ Zs) {
    __shared__ float scratch[8];
    int b = blockIdx.x;
    int k = threadIdx.x;
    int gid = b * NFEAT + k;
    if (gid < NSHADOW * BATCH * 3) Zs[gid] = 0.f;   // zero atomic shadows
    float v1 = in1[b * NFEAT + k];
    float v2 = in2[b * NFEAT + k];
    float n1 = block_reduce_sum256(v1 * v1, scratch);
    float n2 = block_reduce_sum256(v2 * v2, scratch);
    float x1 = v1 / fmaxf(sqrtf(n1), 1e-12f);
    float x2 = v2 / fmaxf(sqrtf(n2), 1e-12f);
    x1n[b * NFEAT + k] = x1;
    int g = b >> 5, r = b & 31;
    Xb[(g * 64 + r) * NFEAT + k]      = f2bf(x1);
    Xb[(g * 64 + 32 + r) * NFEAT + k] = f2bf(x2);
    int t = tgt[b];
    float dv = block_reduce_sum256(x1 * F[(size_t)t * NFEAT + k], scratch);
    if (k == 0) dvec[b] = dv;
}

// ---------------------------------------------------------------------------
// K2: bf16 MFMA logits + shifted-exp reductions; atomics go to shadow
// (blockIdx & 15) -> ~98 same-address collisions instead of 4689.
// ---------------------------------------------------------------------------
__global__ void __launch_bounds__(512)
k_main(const float* __restrict__ F, const short* __restrict__ Xb,
       float* __restrict__ Zs) {
    __shared__ short lfs[MT * NFEAT];  // 32 KB, row stride 512 B, byte-XOR swizzle ((row&7)<<4)
    int tid = threadIdx.x;
    int m0 = blockIdx.x * MT;

    // phase 1: issue all staging loads
    f32x4 v[8];
    #pragma unroll
    for (int rr = 0; rr < 8; ++rr) {
        int c   = rr * 512 + tid;
        int row = c >> 6, cc = c & 63;
        int grow = m0 + row;
        v[rr] = f32x4{0.f, 0.f, 0.f, 0.f};
        if (grow < NSAMP)
            v[rr] = *(const f32x4*)(F + (size_t)grow * NFEAT + cc * 4);
    }
    // phase 2: convert + LDS write
    #pragma unroll
    for (int rr = 0; rr < 8; ++rr) {
        int c   = rr * 512 + tid;
        int row = c >> 6, cc = c & 63;
        uint32_t p0 = (uint32_t)(uint16_t)f2bf(v[rr][0]) | ((uint32_t)(uint16_t)f2bf(v[rr][1]) << 16);
        uint32_t p1 = (uint32_t)(uint16_t)f2bf(v[rr][2]) | ((uint32_t)(uint16_t)f2bf(v[rr][3]) << 16);
        int off = row * 512 + ((cc * 8) ^ ((row & 7) << 4));
        *(u32x2*)((char*)lfs + off) = (u32x2){p0, p1};
    }
    __syncthreads();

    int w = tid >> 6, lane = tid & 63;
    int l15 = lane & 15, lg = lane >> 4;

    f32x4 acc[4][4] = {};  // [m-frag][col-frag]
    const short* xbase = Xb + (size_t)(w * 64) * NFEAT;

    #pragma unroll
    for (int kk = 0; kk < 8; ++kk) {       // K = 256 in steps of 32
        int kb = kk * 64 + lg * 16;
        short8 a[4], bf[4];
        #pragma unroll
        for (int cf = 0; cf < 4; ++cf)
            bf[cf] = *(const short8*)(xbase + (cf * 16 + l15) * NFEAT + kk * 32 + lg * 8);
        #pragma unroll
        for (int mf = 0; mf < 4; ++mf) {
            int row = mf * 16 + l15;
            a[mf] = *(const short8*)((const char*)lfs + row * 512 + (kb ^ ((row & 7) << 4)));
        }
        #pragma unroll
        for (int mf = 0; mf < 4; ++mf)
            #pragma unroll
            for (int cf = 0; cf < 4; ++cf)
                mfma_bf16(acc[mf][cf], a[mf], bf[cf]);
    }

    // epilogue: fixed-shift exp + per-b reduction + shadowed atomics
    int sh = (blockIdx.x & (NSHADOW - 1)) * BATCH;
    #pragma unroll
    for (int cf = 0; cf < 2; ++cf) {
        float z1 = 0.f, z2 = 0.f, s12 = 0.f;
        #pragma unroll
        for (int mf = 0; mf < 4; ++mf) {
            #pragma unroll
            for (int q = 0; q < 4; ++q) {
                int grow = m0 + mf * 16 + lg * 4 + q;
                if (grow < NSAMP) {
                    float l1 = acc[mf][cf][q] * INV_TEMP;
                    float e1 = __expf(l1 - SHIFT);
                    float e2 = __expf(acc[mf][cf + 2][q] * INV_TEMP - SHIFT);
                    z1 += e1; z2 += e2; s12 += e2 * l1;
                }
            }
        }
        z1  += __shfl_xor(z1, 16);  z1  += __shfl_xor(z1, 32);
        z2  += __shfl_xor(z2, 16);  z2  += __shfl_xor(z2, 32);
        s12 += __shfl_xor(s12, 16); s12 += __shfl_xor(s12, 32);
        if (lane < 16) {
            int b = w * 32 + cf * 16 + lane;
            atomicAdd(&Zs[sh + b], z1);
            atomicAdd(&Zs[NSHADOW * BATCH + sh + b], z2);
            atomicAdd(&Zs[2 * NSHADOW * BATCH + sh + b], s12);
        }
    }
}

// ---------------------------------------------------------------------------
// K3 (merged tail): blocks 0..255 -> cluster update; block 256 -> losses.
// ---------------------------------------------------------------------------
__global__ void k_tail(const float* __restrict__ F, const int* __restrict__ tgt,
                       const float* __restrict__ dvec, const float* __restrict__ x1n,
                       const float* __restrict__ Zs, float* __restrict__ out) {
    __shared__ float scratch[8];
    if (blockIdx.x == BATCH) {
        // ---- losses ----
        int b = threadIdx.x;
        float z1 = 0.f, z2 = 0.f, s12 = 0.f;
        #pragma unroll
        for (int j = 0; j < NSHADOW; ++j) {
            z1  += Zs[j * BATCH + b];
            z2  += Zs[NSHADOW * BATCH + j * BATCH + b];
            s12 += Zs[2 * NSHADOW * BATCH + j * BATCH + b];
        }
        float L1   = SHIFT + logf(z1);
        float lpt  = dvec[b] * INV_TEMP - L1;
        float ce12 = s12 / z2;
        float lc = -lpt;
        float ls = (1.f - SMOOTH) * (L1 - ce12) + SMOOTH * (-lpt);
        float sc = block_reduce_sum256(lc, scratch);
        float ss = block_reduce_sum256(ls, scratch);
        if (b == 0) {
            out[0] = sc / (float)BATCH;
            out[1] = ss / (float)BATCH;
        }
        return;
    }
    // ---- cluster update ----
    __shared__ int   stgt[BATCH];
    __shared__ float slog[BATCH];
    int b = blockIdx.x, k = threadIdx.x;
    stgt[k] = tgt[k];
    slog[k] = -dvec[k] * (1.0f / TAU_W);
    __syncthreads();
    int t = stgt[b];
    for (int bp = 0; bp < b; ++bp)
        if (stgt[bp] == t) return;   // uniform: first occurrence owns cluster t
    float m = -1e30f;
    for (int bp = 0; bp < BATCH; ++bp)
        if (stgt[bp] == t) m = fmaxf(m, slog[bp]);
    float denom = 0.f;
    for (int bp = 0; bp < BATCH; ++bp)
        if (stgt[bp] == t) denom += expf(slog[bp] - m);
    float wmean = 0.f;
    for (int bp = 0; bp < BATCH; ++bp)
        if (stgt[bp] == t)
            wmean += expf(slog[bp] - m) * x1n[bp * NFEAT + k];
    wmean /= denom;
    float upd = MOMENTUM * F[(size_t)t * NFEAT + k] + (1.f - MOMENTUM) * wmean;
    float nrm = block_reduce_sum256(upd * upd, scratch);
    out[2 + (size_t)t * NFEAT + k] = upd / fmaxf(sqrtf(nrm), 1e-12f);
}

extern "C" void kernel_launch(void* const* d_in, const int* in_sizes, int n_in,
                              void* d_out, int out_size, void* d_ws, size_t ws_size,
                              hipStream_t stream) {
    const float* in1 = (const float*)d_in[0];
    const float* in2 = (const float*)d_in[1];
    const float* F   = (const float*)d_in[2];
    const int*   tgt = (const int*)d_in[3];
    float* out = (float*)d_out;

    char* ws = (char*)d_ws;
    float* x1n = (float*)ws;                   // 256*256*4 = 262144 B
    short* Xb  = (short*)(ws + 262144);        // 512*256*2 = 262144 B
    float* dv  = (float*)(ws + 524288);        // 1 KB
    float* Zs  = (float*)(ws + 525312);        // 16*256*3*4 = 49152 B

    hipLaunchKernelGGL(k_copy, dim3(2048), dim3(256), 0, stream, F, out);
    hipLaunchKernelGGL(k_prep, dim3(BATCH), dim3(256), 0, stream,
                       in1, in2, F, tgt, x1n, Xb, dv, Zs);
    hipLaunchKernelGGL(k_main, dim3((NSAMP + MT - 1) / MT), dim3(512), 0, stream,
                       F, Xb, Zs);
    hipLaunchKernelGGL(k_tail, dim3(BATCH + 1), dim3(256), 0, stream,
                       F, tgt, dv, x1n, Zs, out);
}

// Round 5
// 299.024 us; speedup vs baseline: 1.1921x; 1.1555x over previous
//
#include <hip/hip_runtime.h>
#include <stdint.h>
#include <stddef.h>

#define TEMP      0.05f
#define INV_TEMP  20.0f
#define MOMENTUM  0.2f
#define SMOOTH    0.1f
#define TAU_W     0.09f
#define NSAMP     100000
#define NFEAT     256
#define BATCH     256
#define SHIFT     20.0f     // |dot/TEMP| <= ~20.2 -> exp(l-20) safe
#define MT        64        // F rows per k_main block
#define TILES     1563      // ceil(NSAMP/MT)
#define NSHADOW   16

typedef float  f32x4  __attribute__((ext_vector_type(4)));
typedef float  f32x2  __attribute__((ext_vector_type(2)));
typedef short  short8 __attribute__((ext_vector_type(8)));
typedef unsigned int u32x2 __attribute__((ext_vector_type(2)));

// fp32 -> bf16 round-to-nearest-even
__device__ __forceinline__ short f2bf(float f) {
    uint32_t u = __builtin_bit_cast(uint32_t, f);
    u = (u + 0x7fffu + ((u >> 16) & 1u)) >> 16;
    return (short)u;
}

__device__ __forceinline__ void mfma_bf16(f32x4& c, short8 a, short8 b) {
    asm("v_mfma_f32_16x16x32_bf16 %0, %1, %2, %0" : "+v"(c) : "v"(a), "v"(b));
}

// async global->LDS DMA, 16B per lane; lds dest is wave-uniform base (+lane*16 by HW)
__device__ __forceinline__ void gload_lds16(const short* g, short* l) {
    __builtin_amdgcn_global_load_lds(
        (const __attribute__((address_space(1))) unsigned int*)(const void*)g,
        (__attribute__((address_space(3))) unsigned int*)(void*)l,
        16, 0, 0);
}

__device__ __forceinline__ float block_reduce_sum256(float v, float* scratch) {
    for (int o = 32; o > 0; o >>= 1) v += __shfl_down(v, o, 64);
    int lane = threadIdx.x & 63, wid = threadIdx.x >> 6;
    if (lane == 0) scratch[wid] = v;
    __syncthreads();
    if (threadIdx.x == 0)
        scratch[4] = scratch[0] + scratch[1] + scratch[2] + scratch[3];
    __syncthreads();
    return scratch[4];
}

// ---------------------------------------------------------------------------
// K0a: F -> {out copy (optional), Fb fragment-linear bf16}.
// Fb layout: [tile][chunk=kk*4+mf][lane=lg*16+l15][8 bf16], so k_main's DMA is
// linear and its ds_read_b128 are lane-linear with immediate offsets.
// Block = 4 rows x 64 f32x4-chunks. Pad rows (>=NSAMP) write zeros to Fb.
// ---------------------------------------------------------------------------
__global__ void __launch_bounds__(256)
k_conv(const float* __restrict__ F, short* __restrict__ Fb, float* outCopy) {
    int t = threadIdx.x;
    int row = blockIdx.x * 4 + (t >> 6);
    int c4  = t & 63;
    f32x4 v = {0.f, 0.f, 0.f, 0.f};
    bool live = row < NSAMP;
    if (live) v = *(const f32x4*)(F + (size_t)row * NFEAT + c4 * 4);
    if (outCopy != nullptr && live) {
        float* op = outCopy + 2 + (size_t)row * NFEAT + c4 * 4;
        __builtin_nontemporal_store(f32x2{v[0], v[1]}, (f32x2*)op);
        __builtin_nontemporal_store(f32x2{v[2], v[3]}, (f32x2*)(op + 2));
    }
    int tile = row >> 6, mf = (row >> 4) & 3, l15 = row & 15;
    int kk = c4 >> 3, lg = (c4 >> 1) & 3, half = c4 & 1;
    uint32_t p0 = (uint32_t)(uint16_t)f2bf(v[0]) | ((uint32_t)(uint16_t)f2bf(v[1]) << 16);
    uint32_t p1 = (uint32_t)(uint16_t)f2bf(v[2]) | ((uint32_t)(uint16_t)f2bf(v[3]) << 16);
    size_t off = (size_t)tile * 16384 + (size_t)(((kk * 4 + mf) * 64 + lg * 16 + l15) * 8) + half * 4;
    *(u32x2*)(Fb + off) = (u32x2){p0, p1};
}

// ---------------------------------------------------------------------------
// K0b (small-ws mode only): plain streaming copy F -> out+2.
// ---------------------------------------------------------------------------
__global__ void __launch_bounds__(256)
k_copy(const float* __restrict__ F, float* __restrict__ out) {
    const size_t total = (size_t)NSAMP * NFEAT / 4;
    size_t stride = (size_t)gridDim.x * 256;
    for (size_t i = (size_t)blockIdx.x * 256 + threadIdx.x; i < total; i += stride) {
        f32x4 v = *(const f32x4*)(F + i * 4);
        float* op = out + 2 + i * 4;
        __builtin_nontemporal_store(f32x2{v[0], v[1]}, (f32x2*)op);
        __builtin_nontemporal_store(f32x2{v[2], v[3]}, (f32x2*)(op + 2));
    }
}

// ---------------------------------------------------------------------------
// K1: normalize x1/x2, emit bf16 X in FRAGMENT-LINEAR layout, exact d[b],
// zero atomic shadows. XbF: [w=cf-group][cf][kk][lane][8 bf16] (256 KB).
// x1[b] -> (w=b>>5, cf=(b&31)>>4);  x2[b] -> (w, cf=2+((b&31)>>4)); l15=b&15.
// ---------------------------------------------------------------------------
__global__ void k_prep(const float* __restrict__ in1, const float* __restrict__ in2,
                       const float* __restrict__ F, const int* __restrict__ tgt,
                       float* __restrict__ x1n, short* __restrict__ XbF,
                       float* __restrict__ dvec, float* __restrict__ Zs) {
    __shared__ float scratch[8];
    int b = blockIdx.x;
    int k = threadIdx.x;
    int gid = b * NFEAT + k;
    if (gid < NSHADOW * BATCH * 3) Zs[gid] = 0.f;
    float v1 = in1[b * NFEAT + k];
    float v2 = in2[b * NFEAT + k];
    float n1 = block_reduce_sum256(v1 * v1, scratch);
    float n2 = block_reduce_sum256(v2 * v2, scratch);
    float x1 = v1 / fmaxf(sqrtf(n1), 1e-12f);
    float x2 = v2 / fmaxf(sqrtf(n2), 1e-12f);
    x1n[b * NFEAT + k] = x1;
    int w = b >> 5, r = b & 31;
    int cf = r >> 4, l15 = r & 15;
    int kk = k >> 5, lg = (k >> 3) & 3, j = k & 7;
    int lane = lg * 16 + l15;
    XbF[(((w * 4 + cf) * 8 + kk) * 64 + lane) * 8 + j]     = f2bf(x1);
    XbF[(((w * 4 + 2 + cf) * 8 + kk) * 64 + lane) * 8 + j] = f2bf(x2);
    int t = tgt[b];
    float dv = block_reduce_sum256(x1 * F[(size_t)t * NFEAT + k], scratch);
    if (k == 0) dvec[b] = dv;
}

// ---------------------------------------------------------------------------
// K2: m97-style. DMA-stage bf16 F tile (4 global_load_lds per wave), then
// kk-loop: lane-linear imm-offset ds_read_b128 (A) + coalesced 1KB loads (B),
// 16 MFMA per kk. Epilogue: shifted exp + shuffle reduce + shadow atomics.
// ---------------------------------------------------------------------------
__global__ void __launch_bounds__(512, 4)
k_main(const short* __restrict__ Fb, const short* __restrict__ XbF,
       float* __restrict__ Zs) {
    __shared__ short lfs[16384];   // 32 KB: [chunk=kk*4+mf][lane][8 bf16]
    int tid = threadIdx.x, w = tid >> 6, lane = tid & 63;
    size_t tbase = (size_t)blockIdx.x * 16384;

    #pragma unroll
    for (int j = 0; j < 4; ++j)
        gload_lds16(Fb + tbase + (size_t)((w * 4 + j) * 512 + lane * 8),
                    &lfs[(w * 4 + j) * 512]);
    __syncthreads();   // compiler emits vmcnt(0) before barrier

    int l15 = lane & 15, lg = lane >> 4;
    int m0 = blockIdx.x * MT;
    f32x4 acc[4][4] = {};
    const short* xw = XbF + (size_t)w * 16384 + lane * 8;

    #pragma unroll
    for (int kk = 0; kk < 8; ++kk) {
        short8 bf0 = *(const short8*)(xw + (0 * 8 + kk) * 512);
        short8 bf1 = *(const short8*)(xw + (1 * 8 + kk) * 512);
        short8 bf2 = *(const short8*)(xw + (2 * 8 + kk) * 512);
        short8 bf3 = *(const short8*)(xw + (3 * 8 + kk) * 512);
        short8 a0 = *(const short8*)(&lfs[(kk * 4 + 0) * 512 + lane * 8]);
        short8 a1 = *(const short8*)(&lfs[(kk * 4 + 1) * 512 + lane * 8]);
        short8 a2 = *(const short8*)(&lfs[(kk * 4 + 2) * 512 + lane * 8]);
        short8 a3 = *(const short8*)(&lfs[(kk * 4 + 3) * 512 + lane * 8]);
        mfma_bf16(acc[0][0], a0, bf0); mfma_bf16(acc[0][1], a0, bf1);
        mfma_bf16(acc[0][2], a0, bf2); mfma_bf16(acc[0][3], a0, bf3);
        mfma_bf16(acc[1][0], a1, bf0); mfma_bf16(acc[1][1], a1, bf1);
        mfma_bf16(acc[1][2], a1, bf2); mfma_bf16(acc[1][3], a1, bf3);
        mfma_bf16(acc[2][0], a2, bf0); mfma_bf16(acc[2][1], a2, bf1);
        mfma_bf16(acc[2][2], a2, bf2); mfma_bf16(acc[2][3], a2, bf3);
        mfma_bf16(acc[3][0], a3, bf0); mfma_bf16(acc[3][1], a3, bf1);
        mfma_bf16(acc[3][2], a3, bf2); mfma_bf16(acc[3][3], a3, bf3);
    }

    // epilogue: C/D layout col=lane&15 (X col), row=lg*4+q (F row in 16-tile)
    int sh = (blockIdx.x & (NSHADOW - 1)) * BATCH;
    #pragma unroll
    for (int cf = 0; cf < 2; ++cf) {
        float z1 = 0.f, z2 = 0.f, s12 = 0.f;
        #pragma unroll
        for (int mf = 0; mf < 4; ++mf) {
            #pragma unroll
            for (int q = 0; q < 4; ++q) {
                int grow = m0 + mf * 16 + lg * 4 + q;
                if (grow < NSAMP) {
                    float l1 = acc[mf][cf][q] * INV_TEMP;
                    float e1 = __expf(l1 - SHIFT);
                    float e2 = __expf(acc[mf][cf + 2][q] * INV_TEMP - SHIFT);
                    z1 += e1; z2 += e2; s12 += e2 * l1;
                }
            }
        }
        z1  += __shfl_xor(z1, 16);  z1  += __shfl_xor(z1, 32);
        z2  += __shfl_xor(z2, 16);  z2  += __shfl_xor(z2, 32);
        s12 += __shfl_xor(s12, 16); s12 += __shfl_xor(s12, 32);
        if (lane < 16) {
            int b = w * 32 + cf * 16 + lane;
            atomicAdd(&Zs[sh + b], z1);
            atomicAdd(&Zs[NSHADOW * BATCH + sh + b], z2);
            atomicAdd(&Zs[2 * NSHADOW * BATCH + sh + b], s12);
        }
    }
}

// ---------------------------------------------------------------------------
// K3: blocks 0..255 -> cluster update; block 256 -> losses.
// ---------------------------------------------------------------------------
__global__ void k_tail(const float* __restrict__ F, const int* __restrict__ tgt,
                       const float* __restrict__ dvec, const float* __restrict__ x1n,
                       const float* __restrict__ Zs, float* __restrict__ out) {
    __shared__ float scratch[8];
    if (blockIdx.x == BATCH) {
        int b = threadIdx.x;
        float z1 = 0.f, z2 = 0.f, s12 = 0.f;
        #pragma unroll
        for (int j = 0; j < NSHADOW; ++j) {
            z1  += Zs[j * BATCH + b];
            z2  += Zs[NSHADOW * BATCH + j * BATCH + b];
            s12 += Zs[2 * NSHADOW * BATCH + j * BATCH + b];
        }
        float L1   = SHIFT + logf(z1);
        float lpt  = dvec[b] * INV_TEMP - L1;
        float ce12 = s12 / z2;
        float lc = -lpt;
        float ls = (1.f - SMOOTH) * (L1 - ce12) + SMOOTH * (-lpt);
        float sc = block_reduce_sum256(lc, scratch);
        float ss = block_reduce_sum256(ls, scratch);
        if (b == 0) {
            out[0] = sc / (float)BATCH;
            out[1] = ss / (float)BATCH;
        }
        return;
    }
    __shared__ int   stgt[BATCH];
    __shared__ float slog[BATCH];
    int b = blockIdx.x, k = threadIdx.x;
    stgt[k] = tgt[k];
    slog[k] = -dvec[k] * (1.0f / TAU_W);
    __syncthreads();
    int t = stgt[b];
    for (int bp = 0; bp < b; ++bp)
        if (stgt[bp] == t) return;   // uniform: first occurrence owns cluster t
    float m = -1e30f;
    for (int bp = 0; bp < BATCH; ++bp)
        if (stgt[bp] == t) m = fmaxf(m, slog[bp]);
    float denom = 0.f;
    for (int bp = 0; bp < BATCH; ++bp)
        if (stgt[bp] == t) denom += expf(slog[bp] - m);
    float wmean = 0.f;
    for (int bp = 0; bp < BATCH; ++bp)
        if (stgt[bp] == t)
            wmean += expf(slog[bp] - m) * x1n[bp * NFEAT + k];
    wmean /= denom;
    float upd = MOMENTUM * F[(size_t)t * NFEAT + k] + (1.f - MOMENTUM) * wmean;
    float nrm = block_reduce_sum256(upd * upd, scratch);
    out[2 + (size_t)t * NFEAT + k] = upd / fmaxf(sqrtf(nrm), 1e-12f);
}

extern "C" void kernel_launch(void* const* d_in, const int* in_sizes, int n_in,
                              void* d_out, int out_size, void* d_ws, size_t ws_size,
                              hipStream_t stream) {
    const float* in1 = (const float*)d_in[0];
    const float* in2 = (const float*)d_in[1];
    const float* F   = (const float*)d_in[2];
    const int*   tgt = (const int*)d_in[3];
    float* out = (float*)d_out;

    char* ws = (char*)d_ws;
    float* x1n = (float*)ws;                   // 256 KB
    short* XbF = (short*)(ws + 262144);        // 256 KB
    float* dv  = (float*)(ws + 524288);        // 1 KB
    float* Zs  = (float*)(ws + 525312);        // 48 KB
    const size_t FB_BYTES = (size_t)TILES * 32768;         // 51,216,384
    const size_t NEED     = 589824 + FB_BYTES;

    if (ws_size >= NEED) {
        short* Fb = (short*)(ws + 589824);     // 16B-aligned
        hipLaunchKernelGGL(k_conv, dim3(TILES * 16), dim3(256), 0, stream, F, Fb, out);
        hipLaunchKernelGGL(k_prep, dim3(BATCH), dim3(256), 0, stream,
                           in1, in2, F, tgt, x1n, XbF, dv, Zs);
        hipLaunchKernelGGL(k_main, dim3(TILES), dim3(512), 0, stream, Fb, XbF, Zs);
        hipLaunchKernelGGL(k_tail, dim3(BATCH + 1), dim3(256), 0, stream,
                           F, tgt, dv, x1n, Zs, out);
    } else {
        // overlay Fb in the tail of d_out, then rewrite out with the true copy
        short* Fb = (short*)((char*)d_out + 51183616);   // +FB_BYTES = 102,400,000 <= out bytes
        hipLaunchKernelGGL(k_conv, dim3(TILES * 16), dim3(256), 0, stream, F, Fb, (float*)nullptr);
        hipLaunchKernelGGL(k_prep, dim3(BATCH), dim3(256), 0, stream,
                           in1, in2, F, tgt, x1n, XbF, dv, Zs);
        hipLaunchKernelGGL(k_main, dim3(TILES), dim3(512), 0, stream, Fb, XbF, Zs);
        hipLaunchKernelGGL(k_copy, dim3(2048), dim3(256), 0, stream, F, out);
        hipLaunchKernelGGL(k_tail, dim3(BATCH + 1), dim3(256), 0, stream,
                           F, tgt, dv, x1n, Zs, out);
    }
}